// Round 1
// baseline (264.167 us; speedup 1.0000x reference)
//
#include <hip/hip_runtime.h>

// Problem geometry
constexpr int B = 2, X = 256, Y = 256, Z = 64;
constexpr int CO = X * Y * Z;                    // channel stride (elements)
constexpr long long N_PTS   = (long long)B * X * Y * Z;          // 8388608
constexpr long long M_CELLS = (long long)B * (X-1) * (Y-1) * (Z-1); // 8193150
constexpr int NLINES = B * X * Y;                // 131072 z-lines
constexpr int BLOCKS = 2048;
constexpr int TPB = 256;                         // 4 waves/block
constexpr int WPB = TPB / 64;
constexpr int TOTAL_WAVES = BLOCKS * WPB;        // 8192 -> 16 lines per wave

#define DXc 0.1f
#define DYc 0.1f
#define EPSc 1e-10f

__global__ __launch_bounds__(TPB) void loss_main(const float* __restrict__ outs,
                                                 const float* __restrict__ tgts,
                                                 double* __restrict__ partial) {
    const int lane = threadIdx.x & 63;
    const int wave = threadIdx.x >> 6;
    const int wglobal = blockIdx.x * WPB + wave;

    double s_pt = 0.0;   // sum of e1+e2+e3 (pointwise losses)
    double s_dv = 0.0;   // sum of num^2/den (divergence loss)

    for (int L = wglobal; L < NLINES; L += TOTAL_WAVES) {
        const int b = L >> 16;        // / (X*Y)
        const int r = L & 65535;
        const int x = r >> 8;         // / Y
        const int y = r & 255;        // % Y

        const float* ob = outs + ((size_t)b * 3 * CO + (size_t)x * Y * Z + (size_t)y * Z);
        const float* tb = tgts + ((size_t)b * 4 * CO + (size_t)x * Y * Z + (size_t)y * Z);
        const int z = lane;

        // ---- pointwise losses (all points valid) ----
        const float bxp = ob[0 * CO + z];
        const float byp = ob[1 * CO + z];
        const float bzp = ob[2 * CO + z];
        const float bxt = tb[0 * CO + z];
        const float byt = tb[1 * CO + z];
        const float bzt = tb[2 * CO + z];

        const float bxt2 = bxt * bxt, byt2 = byt * byt, bzt2 = bzt * bzt;
        const float t1 = bxp * bxp + byp * byp - bxt2 - byt2;
        const float e1 = t1 * t1 / (bxt2 + byt2 + EPSc);
        const float dd = bzp - bzt;
        const float dd2 = dd * dd;
        const float e2 = dd2 * dd2 / (bzt2 + EPSc);
        const float cr = bxp * byt - byp * bxt;
        const float e3 = cr * cr / (bxt2 + byt2 + bzt2 + EPSc);
        s_pt += (double)(e1 + e2 + e3);

        // ---- divergence loss (cells: x<255, y<255, z<63) ----
        if (x < X - 1 && y < Y - 1) {     // wave-uniform branch
            const int dxo = Y * Z;        // +1 in x
            const int dyo = Z;            // +1 in y
            // corner naming: v{i}{j}{k} with i=x-offset, j=y-offset, k=z-offset
            const float bx000 = bxp;
            const float bx100 = ob[0 * CO + dxo + z];
            const float bx010 = ob[0 * CO + dyo + z];
            const float bx110 = ob[0 * CO + dxo + dyo + z];
            const float by000 = byp;
            const float by100 = ob[1 * CO + dxo + z];
            const float by010 = ob[1 * CO + dyo + z];
            const float by110 = ob[1 * CO + dxo + dyo + z];
            const float bz000 = bzp;
            const float bz100 = ob[2 * CO + dxo + z];
            const float bz010 = ob[2 * CO + dyo + z];
            const float bz110 = ob[2 * CO + dxo + dyo + z];
            const float zc000 = tb[3 * CO + z];
            const float zc100 = tb[3 * CO + dxo + z];
            const float zc010 = tb[3 * CO + dyo + z];
            const float zc110 = tb[3 * CO + dxo + dyo + z];

            // k=1 corners come from lane z+1 (stride-1 dim == lane index)
            const float bx001 = __shfl_down(bx000, 1);
            const float bx101 = __shfl_down(bx100, 1);
            const float bx011 = __shfl_down(bx010, 1);
            const float bx111 = __shfl_down(bx110, 1);
            const float by001 = __shfl_down(by000, 1);
            const float by101 = __shfl_down(by100, 1);
            const float by011 = __shfl_down(by010, 1);
            const float by111 = __shfl_down(by110, 1);
            const float bz001 = __shfl_down(bz000, 1);
            const float bz011 = __shfl_down(bz010, 1);
            const float bz101 = __shfl_down(bz100, 1);
            const float bz111 = __shfl_down(bz110, 1);
            const float zc001 = __shfl_down(zc000, 1);
            const float zc101 = __shfl_down(zc100, 1);
            const float zc011 = __shfl_down(zc010, 1);
            const float zc111 = __shfl_down(zc110, 1);

            const float SIXTH = 1.0f / 6.0f;
            float num =
                  0.25f * (bx100 + bx110 + bx101 + bx111) * DYc * 0.5f * (zc101 - zc100 + zc111 - zc110)
                - 0.25f * (bx000 + bx010 + bx001 + bx011) * DYc * 0.5f * (zc001 - zc000 + zc011 - zc010)
                + 0.25f * (by010 + by110 + by011 + by111) * DXc * 0.5f * (zc011 - zc010 + zc111 - zc110)
                - 0.25f * (by000 + by100 + by001 + by101) * DXc * 0.5f * (zc001 - zc000 + zc101 - zc100)
                + 0.25f * (bz001 + bz011 + bz101 + bz111) * DXc * DYc
                - 0.25f * (bz000 + bz010 + bz100 + bz110) * DXc * DYc
                + (bx001 + bx101 + bx111) * DYc * (zc001 - zc101) * SIXTH
                + (bx011 + bx111 + bx101) * DYc * (zc011 - zc111) * SIXTH
                + (by101 + by111 + by011) * DXc * (zc101 - zc111) * SIXTH
                + (by001 + by011 + by111) * DXc * (zc001 - zc011) * SIXTH
                - (bx000 + bx100 + bx110) * DYc * (zc000 - zc100) * SIXTH
                - (bx010 + bx110 + bx100) * DYc * (zc010 - zc110) * SIXTH
                - (by100 + by110 + by010) * DXc * (zc100 - zc110) * SIXTH
                - (by000 + by010 + by110) * DXc * (zc000 - zc010) * SIXTH;

            const float bxc = 0.125f * (bx000 + bx100 + bx010 + bx110 + bx001 + bx101 + bx011 + bx111);
            const float byc = 0.125f * (by000 + by100 + by010 + by110 + by001 + by101 + by011 + by111);
            const float bzc = 0.125f * (bz000 + bz100 + bz010 + bz110 + bz001 + bz101 + bz011 + bz111);
            const float den = bxc * bxc + byc * byc + bzc * bzc + EPSc;

            if (lane < Z - 1) {          // z=63 cell invalid (shfl garbage)
                s_dv += (double)(num * num / den);
            }
        }
    }

    // wave reduction (64 lanes)
    for (int off = 32; off > 0; off >>= 1) {
        s_pt += __shfl_down(s_pt, off);
        s_dv += __shfl_down(s_dv, off);
    }

    __shared__ double lds_pt[WPB];
    __shared__ double lds_dv[WPB];
    if (lane == 0) { lds_pt[wave] = s_pt; lds_dv[wave] = s_dv; }
    __syncthreads();
    if (threadIdx.x == 0) {
        double p = 0.0, d = 0.0;
        #pragma unroll
        for (int w = 0; w < WPB; ++w) { p += lds_pt[w]; d += lds_dv[w]; }
        partial[2 * blockIdx.x]     = p;
        partial[2 * blockIdx.x + 1] = d;
    }
}

__global__ __launch_bounds__(256) void loss_finalize(const double* __restrict__ partial,
                                                     float* __restrict__ out) {
    double s0 = 0.0, s1 = 0.0;
    for (int i = threadIdx.x; i < BLOCKS; i += 256) {
        s0 += partial[2 * i];
        s1 += partial[2 * i + 1];
    }
    const int lane = threadIdx.x & 63;
    const int wave = threadIdx.x >> 6;
    for (int off = 32; off > 0; off >>= 1) {
        s0 += __shfl_down(s0, off);
        s1 += __shfl_down(s1, off);
    }
    __shared__ double l0[4], l1[4];
    if (lane == 0) { l0[wave] = s0; l1[wave] = s1; }
    __syncthreads();
    if (threadIdx.x == 0) {
        double p = 0.0, d = 0.0;
        #pragma unroll
        for (int w = 0; w < 4; ++w) { p += l0[w]; d += l1[w]; }
        // out0 = W_B*loss_b + W_PARALLEL*loss_parallel = 1000 * sum_pt / N
        const double out0 = 1000.0 * (p / (double)N_PTS);
        // out1 = W_DIV * mean(num^2/den) / DX^2 / DY^2
        const double out1 = 100.0 * (d / (double)M_CELLS) / (0.1 * 0.1) / (0.1 * 0.1);
        out[0] = (float)out0;
        out[1] = (float)out1;
    }
}

extern "C" void kernel_launch(void* const* d_in, const int* in_sizes, int n_in,
                              void* d_out, int out_size, void* d_ws, size_t ws_size,
                              hipStream_t stream) {
    const float* outs = (const float*)d_in[0];   // (2,3,256,256,64) f32
    const float* tgts = (const float*)d_in[1];   // (2,4,256,256,64) f32
    float* out = (float*)d_out;                  // 2 scalars f32
    double* partial = (double*)d_ws;             // BLOCKS*2 doubles = 32 KB

    loss_main<<<BLOCKS, TPB, 0, stream>>>(outs, tgts, partial);
    loss_finalize<<<1, 256, 0, stream>>>(partial, out);
}